// Round 5
// baseline (483.474 us; speedup 1.0000x reference)
//
#include <hip/hip_runtime.h>
#include <hip/hip_fp16.h>

typedef unsigned short u16;
typedef __attribute__((ext_vector_type(4))) float f32x4;
typedef __attribute__((ext_vector_type(8))) _Float16 f16x8;
typedef __attribute__((ext_vector_type(4))) _Float16 f16x4;
typedef __attribute__((ext_vector_type(8))) unsigned short u16x8;
typedef __attribute__((ext_vector_type(4))) unsigned short u16x4;

#define DEVI __device__ __forceinline__
#define MASKV (-1000.0f)

DEVI u16 f2h(float f){ __half h = __float2half(f); return __half_as_ushort(h); }
DEVI float h2f(u16 v){ return __half2float(__ushort_as_half(v)); }
DEVI float sigm(float s){ float e = __expf(-fabsf(s)); return (s >= 0.f) ? 1.f/(1.f+e) : e/(1.f+e); }

DEVI void async16(const void* g, void* l){
  __builtin_amdgcn_global_load_lds((__attribute__((address_space(1))) const unsigned int*)g,
                                   (__attribute__((address_space(3))) unsigned int*)l, 16, 0, 0);
}

// ---------------- fused prep: x convert (z=0) + 6 weight transposes (z=1..6), vectorized ----------------
struct PrepArgs {
  const float* src[7];
  u16* dst[7];
  int C[7];
};
__global__ __launch_bounds__(256) void k_prep(PrepArgs p){
  __shared__ u16 t[64][65];
  int z = blockIdx.z;
  int tid = threadIdx.x;
  if (z == 0){
    size_t b0 = (size_t)(blockIdx.y*32 + blockIdx.x)*4096;
    #pragma unroll
    for (int c = 0; c < 4; c++){
      size_t ix = b0 + (size_t)(c*256 + tid)*4;
      f32x4 v = *(const f32x4*)(p.src[0] + ix);
      u16x4 o;
      #pragma unroll
      for (int e=0; e<4; e++) o[e] = f2h(v[e]);
      *(u16x4*)(p.dst[0] + ix) = o;
    }
    return;
  }
  const float* src = p.src[z]; u16* dst = p.dst[z];
  int C = p.C[z];
  int c0 = blockIdx.x*64, r0 = blockIdx.y*64;
  if (c0 >= C) return;
  int tx = tid & 15, ty = tid >> 4;
  #pragma unroll
  for (int rr = 0; rr < 4; rr++){
    int r = r0 + rr*16 + ty, c = c0 + tx*4;
    if (c < C){
      f32x4 v = *(const f32x4*)(src + (size_t)r*C + c);
      #pragma unroll
      for (int e=0; e<4; e++) t[rr*16+ty][tx*4+e] = f2h(v[e]);
    }
  }
  __syncthreads();
  #pragma unroll
  for (int rr = 0; rr < 4; rr++){
    int rr2 = c0 + rr*16 + ty;
    if (rr2 < C){
      u16x4 o;
      #pragma unroll
      for (int e=0; e<4; e++) o[e] = t[tx*4+e][rr*16+ty];
      *(u16x4*)(dst + (size_t)rr2*2048 + r0 + tx*4) = o;
    }
  }
}

// ---------------- transpose u16 [R][C] -> [C][R], batched ----------------
__global__ __launch_bounds__(256) void k_transpose_h(const u16* __restrict__ src, u16* __restrict__ dst,
    int R, int C, long sps, long dps){
  __shared__ u16 t[32][33];
  src += (size_t)blockIdx.z * sps; dst += (size_t)blockIdx.z * dps;
  int c0 = blockIdx.x*32, r0 = blockIdx.y*32;
  int tx = threadIdx.x & 31, ty = threadIdx.x >> 5;
  #pragma unroll
  for (int i = ty; i < 32; i += 8){
    int r = r0 + i, c = c0 + tx;
    if (r < R && c < C) t[i][tx] = src[(size_t)r*C + c];
  }
  __syncthreads();
  #pragma unroll
  for (int i = ty; i < 32; i += 8){
    int rr = c0 + i, cc = r0 + tx;
    if (rr < C && cc < R) dst[(size_t)rr*R + cc] = t[tx][i];
  }
}

// ---------------- QKV + vgate projections: 128x256 tile, 4 waves (1M x 4N), tri-buffer BK=32 ----------------
// Grid 512 blocks -> 2 blocks/CU (72KB LDS): cross-block MFMA/LDS overlap hides barrier drain.
// Wave tile 128x64 (most LDS-efficient). Swizzle: elem(row,slot16B) at slot^((row>>1)&3);
// write side pre-swizzles global col (8*((tid&3)^((tid>>3)&3)), chunk-256-invariant);
// read side XORs slot by (m>>1)&3 -> uniform 4 lanes/slot16 per half-wave (round-3-verified profile).
// Counted vmcnt(6): STG(b_{t+2}) in flight across barrier; never drain to 0 in loop.
struct ProjArgs {
  const u16* xh;
  const u16* wT0; const u16* wT1; const u16* wT2; const u16* wT3;
  u16* q; u16* k; u16* v; u16* vg;
  const float* bvg;
};
__global__ __launch_bounds__(256) void k_proj2(ProjArgs p){
  __shared__ __align__(16) u16 ldsA[3][4096];   // [buf][128 rows x 32 k] 8KB
  __shared__ __align__(16) u16 ldsB[3][8192];   // [buf][256 rows x 32 k] 16KB
  const int z = blockIdx.z;
  const u16* wT = (z==0) ? p.wT0 : (z==1) ? p.wT1 : (z==2) ? p.wT2 : p.wT3;
  const int m0 = blockIdx.y << 7, n0 = blockIdx.x << 8;   // y-major M: consecutive ids share A-panel
  const int tid = threadIdx.x, wn = tid >> 6, l = tid & 63;
  const int qq = l >> 4, m = l & 15;
  const int sw = (qq ^ ((m >> 1) & 3)) * 8;               // read-side swizzled slot (elem units)
  const int colsw = 8 * ((tid & 3) ^ ((tid >> 3) & 3));   // inverse-swizzled source col
  const int r0 = tid >> 2;
  const u16* aS0 = p.xh + (size_t)(m0 + r0) * 2048 + colsw;
  const u16* aS1 = aS0 + (size_t)64 * 2048;
  const u16* bS0 = wT   + (size_t)(n0 + r0) * 2048 + colsw;
  const u16* bS1 = bS0 + (size_t)64 * 2048;
  const u16* bS2 = bS0 + (size_t)128 * 2048;
  const u16* bS3 = bS0 + (size_t)192 * 2048;

  f32x4 acc[8][4];
  { f32x4 zr = {0.f,0.f,0.f,0.f};
    #pragma unroll
    for (int i=0;i<8;i++)
      #pragma unroll
      for (int j=0;j<4;j++) acc[i][j] = zr; }

#define STG(buf,kt) do{ \
    async16(aS0 + (size_t)(kt)*32, &ldsA[buf][tid*8]); \
    async16(aS1 + (size_t)(kt)*32, &ldsA[buf][tid*8 + 2048]); \
    async16(bS0 + (size_t)(kt)*32, &ldsB[buf][tid*8]); \
    async16(bS1 + (size_t)(kt)*32, &ldsB[buf][tid*8 + 2048]); \
    async16(bS2 + (size_t)(kt)*32, &ldsB[buf][tid*8 + 4096]); \
    async16(bS3 + (size_t)(kt)*32, &ldsB[buf][tid*8 + 6144]); }while(0)

#define COMPUTE(buf) do{ \
    f16x8 bf0 = *(const f16x8*)(&ldsB[buf][(wn*64 +  0 + m)*32 + sw]); \
    f16x8 bf1 = *(const f16x8*)(&ldsB[buf][(wn*64 + 16 + m)*32 + sw]); \
    f16x8 bf2 = *(const f16x8*)(&ldsB[buf][(wn*64 + 32 + m)*32 + sw]); \
    f16x8 bf3 = *(const f16x8*)(&ldsB[buf][(wn*64 + 48 + m)*32 + sw]); \
    __builtin_amdgcn_s_setprio(1); \
    _Pragma("unroll") \
    for (int i = 0; i < 8; i++){ \
      f16x8 a = *(const f16x8*)(&ldsA[buf][(i*16 + m)*32 + sw]); \
      acc[i][0] = __builtin_amdgcn_mfma_f32_16x16x32_f16(a, bf0, acc[i][0], 0,0,0); \
      acc[i][1] = __builtin_amdgcn_mfma_f32_16x16x32_f16(a, bf1, acc[i][1], 0,0,0); \
      acc[i][2] = __builtin_amdgcn_mfma_f32_16x16x32_f16(a, bf2, acc[i][2], 0,0,0); \
      acc[i][3] = __builtin_amdgcn_mfma_f32_16x16x32_f16(a, bf3, acc[i][3], 0,0,0); \
    } \
    __builtin_amdgcn_s_setprio(0); }while(0)

  // prologue: stage buf0(kt0), buf1(kt1); wait buf0 (12 outstanding -> 6)
  STG(0,0); STG(1,1);
  asm volatile("s_waitcnt vmcnt(6)" ::: "memory");
  __builtin_amdgcn_s_barrier();

  int cur = 0;
  for (int t = 0; t < 62; t++){
    int nb = (cur == 0) ? 2 : cur - 1;        // (cur+2)%3
    STG(nb, t+2);
    COMPUTE(cur);
    asm volatile("s_waitcnt vmcnt(6)" ::: "memory");   // b_{t+1} retired; b_{t+2} stays in flight
    __builtin_amdgcn_s_barrier();
    cur = (cur == 2) ? 0 : cur + 1;
  }
  // t = 62: no stage; drain remaining (buf for t=63)
  COMPUTE(cur);
  asm volatile("s_waitcnt vmcnt(0)" ::: "memory");
  __builtin_amdgcn_s_barrier();
  cur = (cur == 2) ? 0 : cur + 1;
  // t = 63
  COMPUTE(cur);

  u16* dst3 = (z==0) ? p.q : (z==1) ? p.k : p.v;
  #pragma unroll
  for (int i=0;i<8;i++)
  #pragma unroll
  for (int j=0;j<4;j++)
  #pragma unroll
  for (int r=0;r<4;r++){
    int gr = m0 + i*16 + qq*4 + r;
    int gc = n0 + wn*64 + j*16 + m;
    float v = acc[i][j][r];
    if (z == 3){
      p.vg[(size_t)gr*2048 + gc] = f2h(sigm(v + p.bvg[gc]));
    } else {
      int b = gr >> 10, ii = gr & 1023, h = gc >> 7, d = gc & 127;
      dst3[(((size_t)(b*16 + h))*1024 + ii)*128 + d] = f2h(v);
    }
  }
#undef STG
#undef COMPUTE
}

// ---------------- head gate: sigmoid(x @ w_hgate + b), K split over 4 waves ----------------
__global__ __launch_bounds__(256) void k_hgate(const u16* __restrict__ xh, const u16* __restrict__ whgT,
    const float* __restrict__ bhg, float* __restrict__ hg){
  __shared__ float red[4][256];
  int tid = threadIdx.x, w = tid>>6, l = tid&63, q = l>>4, m = l&15;
  int t0 = blockIdx.x*16;
  f32x4 acc = {0.f,0.f,0.f,0.f};
  const u16* xr = xh   + (size_t)(t0 + m)*2048 + w*512;
  const u16* br = whgT + (size_t)m*2048 + w*512;
  #pragma unroll 4
  for (int k = 0; k < 512; k += 32){
    f16x8 a = *(const f16x8*)(xr + k + q*8);
    f16x8 b = *(const f16x8*)(br + k + q*8);
    acc = __builtin_amdgcn_mfma_f32_16x16x32_f16(a, b, acc, 0, 0, 0);
  }
  #pragma unroll
  for (int r = 0; r < 4; r++) red[w][(q*4+r)*16 + m] = acc[r];
  __syncthreads();
  float v = red[0][tid] + red[1][tid] + red[2][tid] + red[3][tid];
  int tl = tid >> 4, h = tid & 15;
  hg[(size_t)(t0 + tl)*16 + h] = sigm(v + bhg[h]);
}

// ---------------- q,k l2norm + rotary (in place) + CoPE logits L ----------------
__global__ __launch_bounds__(256) void k_normrope(u16* __restrict__ qb, u16* __restrict__ kb,
    const float* __restrict__ freqs, const float* __restrict__ cope, float* __restrict__ L){
  __shared__ float ce[2048];
  int tid = threadIdx.x;
  for (int i2 = tid; i2 < 2048; i2 += 256) ce[i2] = cope[i2];
  __syncthreads();
  int w = tid >> 6, l = tid & 63;
  int r = blockIdx.x*4 + w;            // 0..65535
  int isq = (r < 32768) ? 1 : 0;
  int rr = isq ? r : r - 32768;
  int i = rr & 1023;
  u16* base = (isq ? qb : kb) + (size_t)rr*128;
  float v0 = h2f(base[2*l]), v1 = h2f(base[2*l+1]);
  float ss = v0*v0 + v1*v1;
  #pragma unroll
  for (int off = 1; off < 64; off <<= 1) ss += __shfl_xor(ss, off);
  float rn = 1.f / fmaxf(sqrtf(ss), 1e-12f);
  v0 *= rn; v1 *= rn;
  float f = freqs[i*128 + 2*l];
  float sn, cs; sincosf(f, &sn, &cs);
  float o0 = v0*cs - v1*sn, o1 = v1*cs + v0*sn;
  base[2*l] = f2h(o0); base[2*l+1] = f2h(o1);
  if (isq){
    #pragma unroll
    for (int p = 0; p < 16; p++){
      float part = o0*ce[p*128 + 2*l] + o1*ce[p*128 + 2*l + 1];
      #pragma unroll
      for (int off = 1; off < 64; off <<= 1) part += __shfl_xor(part, off);
      if (l == p) L[(size_t)rr*16 + p] = part;
    }
  }
}

// ---------------- sim = 10*q k^T: A-resident 64-row tile, loop j-tiles ----------------
__global__ __launch_bounds__(256) void k_qk(const u16* __restrict__ qb, const u16* __restrict__ kb,
    u16* __restrict__ S){
  __shared__ __align__(16) u16 As[8192];    // 4 chunks x 64 rows x 32
  __shared__ __align__(16) u16 Bs[16384];   // 4 chunks x 128 rows x 32
  int bh = blockIdx.y;
  int bx = 15 - (int)blockIdx.x;            // heavy blocks first
  int i0 = bx*64, it = bx >> 1;
  int njt = (bx + 2) >> 1;
  int tid = threadIdx.x, w = tid>>6, l = tid&63, q = l>>4, m = l&15, wm = w&1, wn = w>>1;
  const u16* qbase = qb + (size_t)bh*131072;
  const u16* kbase = kb + (size_t)bh*131072;
  // stage A once (resident)
  #pragma unroll
  for (int sub = 0; sub < 4; sub++){
    int row = w*16 + (l>>2);
    async16(qbase + (size_t)(i0 + row)*128 + sub*32 + (l&3)*8, As + sub*2048 + (w*16)*32);
  }
  u16* dstbase = S + ((size_t)bh*36 + (it*(it+1))/2)*16384 + (size_t)((bx&1)*64)*128;
  for (int jt = 0; jt < njt; jt++){
    __syncthreads();
    #pragma unroll
    for (int sub = 0; sub < 4; sub++)
      #pragma unroll
      for (int p = 0; p < 2; p++){
        int row = w*32 + p*16 + (l>>2);
        async16(kbase + (size_t)(jt*128 + row)*128 + sub*32 + (l&3)*8,
                Bs + sub*4096 + (w*32 + p*16)*32);
      }
    __syncthreads();
    f32x4 acc[2][4];
    { f32x4 z = {0.f,0.f,0.f,0.f};
      #pragma unroll
      for (int a2=0;a2<2;a2++)
        #pragma unroll
        for (int b2=0;b2<4;b2++) acc[a2][b2] = z; }
    #pragma unroll
    for (int kc = 0; kc < 4; kc++){
      f16x8 af[2], bf[4];
      #pragma unroll
      for (int t = 0; t < 2; t++) af[t] = *(const f16x8*)(As + kc*2048 + (wm*32 + t*16 + m)*32 + q*8);
      #pragma unroll
      for (int t = 0; t < 4; t++) bf[t] = *(const f16x8*)(Bs + kc*4096 + (wn*64 + t*16 + m)*32 + q*8);
      #pragma unroll
      for (int a2 = 0; a2 < 2; a2++)
        #pragma unroll
        for (int b2 = 0; b2 < 4; b2++)
          acc[a2][b2] = __builtin_amdgcn_mfma_f32_16x16x32_f16(af[a2], bf[b2], acc[a2][b2], 0, 0, 0);
    }
    u16* dst = dstbase + (size_t)jt*16384;
    #pragma unroll
    for (int ti=0; ti<2; ti++)
    #pragma unroll
    for (int tj=0; tj<4; tj++)
    #pragma unroll
    for (int r=0; r<4; r++){
      int iloc = wm*32 + ti*16 + q*4 + r;
      int jloc = wn*64 + tj*16 + m;
      float v = acc[ti][tj][r] * 10.f;
      if (jt*128 + jloc > i0 + iloc) v = MASKV;
      dst[(size_t)iloc*128 + jloc] = f2h(v);
    }
  }
}

// ---------------- th_pre mix + CoPE + online softmax stats (in-place S) ----------------
struct CopeArgs { const u16* S; const float* L; const float* thpre; u16* Sout; float* ml; };
__global__ __launch_bounds__(1024) void k_cope(CopeArgs pa){
  __shared__ u16 raw[16*276];       // [g][ii*68 + j], padded strides: conflict-free b64
  __shared__ float thsh[256];       // th_pre[h][g]
  __shared__ float Lsh[1024];       // [h][ii][p]
  int b = blockIdx.y;
  int i0 = (int)(gridDim.x - 1 - blockIdx.x) * 4;   // heavy blocks first
  int tid = threadIdx.x, w = tid>>6, l = tid&63;
  int h = w;                                         // 16 waves = 16 heads
  if (tid < 256) thsh[tid] = pa.thpre[tid];
  Lsh[tid] = pa.L[ ((size_t)((b*16 + (tid>>6))*1024) + i0 + ((tid>>4)&3))*16 + (tid&15) ];
  __syncthreads();
  float th_r[16];
  #pragma unroll
  for (int g = 0; g < 16; g++) th_r[g] = thsh[h*16 + g];
  int ii = l >> 4, j0 = (l & 15)*4;
  int i = i0 + ii, it1 = i >> 7, iloc = i & 127;
  const float* Lrow = Lsh + h*64 + ii*16;
  float carry = 0.f, mrun = -1e30f, lrun = 0.f;
  int tmax = (i0 + 3) >> 6;
  for (int t = tmax; t >= 0; t--){
    int jt1 = (t*64) >> 7, jo = (t*64) & 127;
    __syncthreads();
    {
      int e = tid*4;                 // [0,4096)
      int g = e >> 8, r = e & 255;
      int si = r >> 6, j = r & 63;
      int irow = i0 + si; int it2 = irow >> 7, il2 = irow & 127;
      const u16* src = pa.S + ((size_t)((b*16+g)*36 + (it2*(it2+1))/2 + jt1))*16384
                           + (size_t)il2*128 + jo + j;
      *(u16x4*)(raw + g*276 + si*68 + j) = *(const u16x4*)src;
    }
    __syncthreads();
    float s0=0.f, s1=0.f, s2=0.f, s3=0.f;
    #pragma unroll
    for (int g = 0; g < 16; g++){
      u16x4 v = *(const u16x4*)(raw + g*276 + ii*68 + j0);
      float tg = th_r[g];
      s0 += tg*h2f(v[0]); s1 += tg*h2f(v[1]); s2 += tg*h2f(v[2]); s3 += tg*h2f(v[3]);
    }
    // gates + segmented suffix scan (in-lane 4 + cross-lane 16)
    float g0 = sigm(s0), g1 = sigm(s1), g2 = sigm(s2), g3 = sigm(s3);
    float c3 = g3, c2 = g2 + c3, c1 = g1 + c2, c0 = g0 + c1;
    float T = c0, Tacc = T;
    #pragma unroll
    for (int off = 1; off < 16; off <<= 1){
      float tv = __shfl(Tacc, (l + off) & 63);
      if (((l & 15) + off) < 16) Tacc += tv;
    }
    float Rh = Tacc - T;                         // sum over higher lanes in group
    float rowtot = __shfl(Tacc, l & 48);         // group-first lane = full tile sum
    float sf[4];
    float cc[4] = {c0, c1, c2, c3};
    float ssv[4] = {s0, s1, s2, s3};
    #pragma unroll
    for (int c = 0; c < 4; c++){
      float pos = fminf(cc[c] + Rh + carry, 15.f);
      float pf = floorf(pos);
      float wi = pos - pf;
      int ic = (int)ceilf(pos), ifl = (int)pf;
      float v = ssv[c] + Lrow[ic]*wi + Lrow[ifl]*(1.f - wi);
      sf[c] = v;
    }
    carry += rowtot;
    u16x4 ov;
    #pragma unroll
    for (int c = 0; c < 4; c++){ ov[c] = f2h(sf[c]); sf[c] = h2f(ov[c]); }
    *(u16x4*)(pa.Sout + ((size_t)((b*16+h)*36 + (it1*(it1+1))/2 + jt1))*16384
              + (size_t)iloc*128 + jo + j0) = ov;
    float M = fmaxf(fmaxf(sf[0], sf[1]), fmaxf(sf[2], sf[3]));
    #pragma unroll
    for (int off = 1; off < 16; off <<= 1) M = fmaxf(M, __shfl_xor(M, off));
    float mnew = fmaxf(mrun, M);
    float es = __expf(fminf(sf[0]-mnew,0.f)) + __expf(fminf(sf[1]-mnew,0.f))
             + __expf(fminf(sf[2]-mnew,0.f)) + __expf(fminf(sf[3]-mnew,0.f));
    #pragma unroll
    for (int off = 1; off < 16; off <<= 1) es += __shfl_xor(es, off);
    lrun = lrun*__expf(fminf(mrun - mnew, 0.f)) + es;
    mrun = mnew;
  }
  if ((l & 15) == 0){
    size_t bix = (size_t)(b*16 + h)*1024 + i0 + ii;
    pa.ml[bix] = mrun;
    pa.ml[32768 + bix] = 1.f/fmaxf(lrun, 1e-30f);
  }
}

// ---------------- softmax normalize + th_post mix (packed fp16, in-place S -> attn2) ----------------
struct PostArgs { const u16* S; const float* ml; const float* thpost; u16* Sout; };
__global__ __launch_bounds__(256) void k_postmix(PostArgs pa){
  __shared__ u16 at[16*1040];        // [g][e], stride 1040
  __shared__ _Float16 thsh[256];
  __shared__ float mh[128], rlh[128];
  int tile = blockIdx.x >> 4, sub = blockIdx.x & 15, b = blockIdx.y;
  int it = 0;
  #pragma unroll
  for (int t2=1; t2<8; t2++) if (tile >= (t2*(t2+1))/2) it = t2;
  int tid = threadIdx.x;
  thsh[tid] = (_Float16)pa.thpost[tid];
  if (tid < 128){
    int g = tid >> 3, ii = tid & 7;
    size_t ix = (size_t)(b*16+g)*1024 + it*128 + sub*8 + ii;
    mh[tid] = pa.ml[ix]; rlh[tid] = pa.ml[32768 + ix];
  }
  __syncthreads();
  {
    int g = tid >> 4, l16 = tid & 15;
    const u16* src = pa.S + ((size_t)((b*16+g)*36 + tile))*16384 + sub*1024;
    #pragma unroll
    for (int c = 0; c < 16; c++){
      int e = c*64 + l16*4;
      int ii = e >> 7;
      float mm = mh[g*8+ii], rr = rlh[g*8+ii];
      u16x4 sv = *(const u16x4*)(src + e);
      u16x4 o;
      #pragma unroll
      for (int z2=0; z2<4; z2++) o[z2] = f2h(__expf(fminf(h2f(sv[z2]) - mm, 0.f)) * rr);
      *(u16x4*)(at + g*1040 + e) = o;
    }
  }
  __syncthreads();
  int h = tid >> 4, c16 = tid & 15;
  _Float16 th_h[16];
  #pragma unroll
  for (int g = 0; g < 16; g++) th_h[g] = thsh[h*16 + g];
  u16* dst = pa.Sout + ((size_t)((b*16+h)*36 + tile))*16384 + sub*1024;
  #pragma unroll
  for (int k = 0; k < 16; k++){
    int e = c16*4 + k*64;
    f16x4 a = {0,0,0,0};
    #pragma unroll
    for (int g = 0; g < 16; g++){
      f16x4 v = *(const f16x4*)(at + g*1040 + e);
      a += v * th_h[g];
    }
    *(f16x4*)(dst + e) = a;
  }
}

// ---------------- out = attn2 @ v, fused head/value gates, BK=128 chunks ----------------
struct PvArgs { const u16* S; const u16* vT; const float* hg; const u16* vg; u16* gated; };
__global__ __launch_bounds__(256) void k_pv(PvArgs pa){
  __shared__ __align__(16) u16 As[8192];    // 4 sub x 64 rows x 32
  __shared__ __align__(16) u16 Bs[16384];   // 4 sub x 128 rows x 32
  int bh = blockIdx.y, b = bh >> 4, h = bh & 15;
  int bx = 15 - (int)blockIdx.x;            // heavy blocks first
  int i0 = bx*64, it = bx >> 1;
  int nc = (bx + 2) >> 1;
  int tid = threadIdx.x, w = tid>>6, l = tid&63, q = l>>4, m = l&15, wm = w&1, wn = w>>1;
  const u16* abase = pa.S + ((size_t)bh*36 + (it*(it+1))/2)*16384 + (size_t)((bx&1)*64)*128;
  const u16* vt    = pa.vT + (size_t)bh*131072;
  f32x4 acc[2][4];
  { f32x4 z = {0.f,0.f,0.f,0.f};
    #pragma unroll
    for (int a2=0;a2<2;a2++)
      #pragma unroll
      for (int b2=0;b2<4;b2++) acc[a2][b2] = z; }
  for (int jc = 0; jc < nc; jc++){
    __syncthreads();
    #pragma unroll
    for (int sub = 0; sub < 4; sub++){
      int row = w*16 + (l>>2);
      async16(abase + (size_t)jc*16384 + (size_t)row*128 + sub*32 + (l&3)*8,
              As + sub*2048 + (w*16)*32);
      #pragma unroll
      for (int p = 0; p < 2; p++){
        int brow = w*32 + p*16 + (l>>2);
        async16(vt + (size_t)brow*1024 + jc*128 + sub*32 + (l&3)*8,
                Bs + sub*4096 + (w*32 + p*16)*32);
      }
    }
    __syncthreads();
    #pragma unroll
    for (int kc = 0; kc < 4; kc++){
      f16x8 af[2], bf[4];
      #pragma unroll
      for (int t = 0; t < 2; t++) af[t] = *(const f16x8*)(As + kc*2048 + (wm*32 + t*16 + m)*32 + q*8);
      #pragma unroll
      for (int t = 0; t < 4; t++) bf[t] = *(const f16x8*)(Bs + kc*4096 + (wn*64 + t*16 + m)*32 + q*8);
      #pragma unroll
      for (int a2 = 0; a2 < 2; a2++)
        #pragma unroll
        for (int b2 = 0; b2 < 4; b2++)
          acc[a2][b2] = __builtin_amdgcn_mfma_f32_16x16x32_f16(af[a2], bf[b2], acc[a2][b2], 0, 0, 0);
    }
  }
  #pragma unroll
  for (int ti=0; ti<2; ti++)
  #pragma unroll
  for (int tj=0; tj<4; tj++)
  #pragma unroll
  for (int r=0; r<4; r++){
    int i = i0 + wm*32 + ti*16 + q*4 + r;
    int d = wn*64 + tj*16 + m;
    int tok = b*1024 + i;
    float v = acc[ti][tj][r] * pa.hg[(size_t)tok*16 + h] * h2f(pa.vg[(size_t)tok*2048 + h*128 + d]);
    if (v != v) v = 333.f;           // NaN tag: PV-level
    pa.gated[(size_t)tok*2048 + h*128 + d] = f2h(v);
  }
}

// ---------------- final projection -> f32 d_out (M=64 tiles, 512 blocks) ----------------
__global__ __launch_bounds__(256) void k_out(const u16* __restrict__ gated, const u16* __restrict__ woT,
    float* __restrict__ out){
  __shared__ __align__(16) u16 As[2048];
  __shared__ __align__(16) u16 Bs[4096];
  int bx = blockIdx.x;                // col tile (16)
  int by = blockIdx.y;                // row tile (32)
  int trow0 = by*64, c0 = bx*128;
  int tid = threadIdx.x, w = tid>>6, l = tid&63, q = l>>4, m = l&15, wm = w&1, wn = w>>1;
  f32x4 acc[2][4];
  { f32x4 z = {0.f,0.f,0.f,0.f};
    #pragma unroll
    for (int a2=0;a2<2;a2++)
      #pragma unroll
      for (int b2=0;b2<4;b2++) acc[a2][b2] = z; }
  for (int k0 = 0; k0 < 2048; k0 += 32){
    __syncthreads();
    {
      int row = w*16 + (l>>2);
      async16(gated + (size_t)(trow0 + row)*2048 + k0 + (l&3)*8, As + (w*16)*32);
    }
    #pragma unroll
    for (int p = 0; p < 2; p++){
      int row = w*32 + p*16 + (l>>2);
      async16(woT + (size_t)(c0 + row)*2048 + k0 + (l&3)*8, Bs + (w*32 + p*16)*32);
    }
    __syncthreads();
    f16x8 af[2], bf[4];
    #pragma unroll
    for (int t = 0; t < 2; t++) af[t] = *(const f16x8*)(As + (wm*32 + t*16 + m)*32 + q*8);
    #pragma unroll
    for (int t = 0; t < 4; t++) bf[t] = *(const f16x8*)(Bs + (wn*64 + t*16 + m)*32 + q*8);
    #pragma unroll
    for (int a2 = 0; a2 < 2; a2++)
      #pragma unroll
      for (int b2 = 0; b2 < 4; b2++)
        acc[a2][b2] = __builtin_amdgcn_mfma_f32_16x16x32_f16(af[a2], bf[b2], acc[a2][b2], 0, 0, 0);
  }
  #pragma unroll
  for (int ti=0; ti<2; ti++)
  #pragma unroll
  for (int tj=0; tj<4; tj++)
  #pragma unroll
  for (int r=0; r<4; r++){
    int trow = trow0 + wm*32 + ti*16 + q*4 + r;
    int col  = c0 + wn*64 + tj*16 + m;
    float o = acc[ti][tj][r];
    if (o != o) o = 911.f;           // NaN tag: output-GEMM level
    out[(size_t)trow*2048 + col] = o;
  }
}

extern "C" void kernel_launch(void* const* d_in, const int* in_sizes, int n_in,
                              void* d_out, int out_size, void* d_ws, size_t ws_size,
                              hipStream_t stream){
  const float* x      = (const float*)d_in[0];
  const float* freqs  = (const float*)d_in[1];
  const float* w_q    = (const float*)d_in[2];
  const float* w_k    = (const float*)d_in[3];
  const float* w_v    = (const float*)d_in[4];
  const float* cope   = (const float*)d_in[5];
  const float* thpre  = (const float*)d_in[6];
  const float* thpost = (const float*)d_in[7];
  const float* w_vg   = (const float*)d_in[8];
  const float* b_vg   = (const float*)d_in[9];
  const float* w_hg   = (const float*)d_in[10];
  const float* b_hg   = (const float*)d_in[11];
  const float* w_out  = (const float*)d_in[12];

  char* ws = (char*)d_ws;
  size_t off = 0;
  auto alloc = [&](size_t bytes)->char*{ char* r = ws + off; off += (bytes + 255) & ~(size_t)255; return r; };
  u16*   xh    = (u16*)  alloc(8388608);
  u16*   wqT   = (u16*)  alloc(8388608);
  u16*   wkT   = (u16*)  alloc(8388608);
  u16*   wvT   = (u16*)  alloc(8388608);
  u16*   wvgT  = (u16*)  alloc(8388608);
  u16*   woT   = (u16*)  alloc(8388608);
  u16*   whgT  = (u16*)  alloc(65536);
  u16*   qb    = (u16*)  alloc(8388608);
  u16*   kb    = (u16*)  alloc(8388608);
  u16*   vb    = (u16*)  alloc(8388608);
  u16*   vTT   = (u16*)  alloc(8388608);
  u16*   vg    = (u16*)  alloc(8388608);
  u16*   gated = (u16*)  alloc(8388608);
  float* L     = (float*)alloc(2097152);
  float* hg    = (float*)alloc(131072);
  float* ml    = (float*)alloc(262144);
  u16*   S     = (u16*)  alloc(37748736);

  dim3 b256(256);
  PrepArgs pp;
  pp.src[0]=x;    pp.dst[0]=xh;   pp.C[0]=2048;
  pp.src[1]=w_q;  pp.dst[1]=wqT;  pp.C[1]=2048;
  pp.src[2]=w_k;  pp.dst[2]=wkT;  pp.C[2]=2048;
  pp.src[3]=w_v;  pp.dst[3]=wvT;  pp.C[3]=2048;
  pp.src[4]=w_vg; pp.dst[4]=wvgT; pp.C[4]=2048;
  pp.src[5]=w_out;pp.dst[5]=woT;  pp.C[5]=2048;
  pp.src[6]=w_hg; pp.dst[6]=whgT; pp.C[6]=16;
  k_prep<<<dim3(32,32,7), b256, 0, stream>>>(pp);

  ProjArgs pa{ xh, wqT, wkT, wvT, wvgT, qb, kb, vb, vg, b_vg };
  k_proj2<<<dim3(8,16,4), dim3(256), 0, stream>>>(pa);
  k_hgate<<<dim3(128), b256, 0, stream>>>(xh, whgT, b_hg, hg);
  k_transpose_h<<<dim3(4,32,32), b256, 0, stream>>>(vb, vTT, 1024, 128, 131072L, 131072L);
  k_normrope<<<dim3(16384), b256, 0, stream>>>(qb, kb, freqs, cope, L);
  k_qk<<<dim3(16,32), b256, 0, stream>>>(qb, kb, S);
  CopeArgs ca{ S, L, thpre, S, ml };
  k_cope<<<dim3(256,2), dim3(1024), 0, stream>>>(ca);
  PostArgs po{ S, ml, thpost, S };
  k_postmix<<<dim3(576,2), b256, 0, stream>>>(po);
  PvArgs pv{ S, vTT, hg, vg, gated };
  k_pv<<<dim3(16,32), b256, 0, stream>>>(pv);
  k_out<<<dim3(16,32), b256, 0, stream>>>(gated, woT, (float*)d_out);
}

// Round 6
// 454.976 us; speedup vs baseline: 1.0626x; 1.0626x over previous
//
#include <hip/hip_runtime.h>
#include <hip/hip_fp16.h>

typedef unsigned short u16;
typedef __attribute__((ext_vector_type(4))) float f32x4;
typedef __attribute__((ext_vector_type(8))) _Float16 f16x8;
typedef __attribute__((ext_vector_type(4))) _Float16 f16x4;
typedef __attribute__((ext_vector_type(8))) unsigned short u16x8;
typedef __attribute__((ext_vector_type(4))) unsigned short u16x4;

#define DEVI __device__ __forceinline__
#define MASKV (-1000.0f)

DEVI u16 f2h(float f){ __half h = __float2half(f); return __half_as_ushort(h); }
DEVI float h2f(u16 v){ return __half2float(__ushort_as_half(v)); }
DEVI float sigm(float s){ float e = __expf(-fabsf(s)); return (s >= 0.f) ? 1.f/(1.f+e) : e/(1.f+e); }

DEVI void async16(const void* g, void* l){
  __builtin_amdgcn_global_load_lds((__attribute__((address_space(1))) const unsigned int*)g,
                                   (__attribute__((address_space(3))) unsigned int*)l, 16, 0, 0);
}

// ---------------- fused prep: x convert (z=0) + 6 weight transposes (z=1..6), vectorized ----------------
struct PrepArgs {
  const float* src[7];
  u16* dst[7];
  int C[7];
};
__global__ __launch_bounds__(256) void k_prep(PrepArgs p){
  __shared__ u16 t[64][65];
  int z = blockIdx.z;
  int tid = threadIdx.x;
  if (z == 0){
    size_t b0 = (size_t)(blockIdx.y*32 + blockIdx.x)*4096;
    #pragma unroll
    for (int c = 0; c < 4; c++){
      size_t ix = b0 + (size_t)(c*256 + tid)*4;
      f32x4 v = *(const f32x4*)(p.src[0] + ix);
      u16x4 o;
      #pragma unroll
      for (int e=0; e<4; e++) o[e] = f2h(v[e]);
      *(u16x4*)(p.dst[0] + ix) = o;
    }
    return;
  }
  const float* src = p.src[z]; u16* dst = p.dst[z];
  int C = p.C[z];
  int c0 = blockIdx.x*64, r0 = blockIdx.y*64;
  if (c0 >= C) return;
  int tx = tid & 15, ty = tid >> 4;
  #pragma unroll
  for (int rr = 0; rr < 4; rr++){
    int r = r0 + rr*16 + ty, c = c0 + tx*4;
    if (c < C){
      f32x4 v = *(const f32x4*)(src + (size_t)r*C + c);
      #pragma unroll
      for (int e=0; e<4; e++) t[rr*16+ty][tx*4+e] = f2h(v[e]);
    }
  }
  __syncthreads();
  #pragma unroll
  for (int rr = 0; rr < 4; rr++){
    int rr2 = c0 + rr*16 + ty;
    if (rr2 < C){
      u16x4 o;
      #pragma unroll
      for (int e=0; e<4; e++) o[e] = t[tx*4+e][rr*16+ty];
      *(u16x4*)(dst + (size_t)rr2*2048 + r0 + tx*4) = o;
    }
  }
}

// ---------------- QKV + vgate projections: 256x256 tile, 8-phase counted-vmcnt (round-3 verified) ----------------
// 8 waves (2M x 4N), BK=64, parity double-buffer. LDS swizzle: element(row,slot16B)
// stored at slot ^ (row&7); write side pre-swizzles global source (slot (l&7)^(l>>3)),
// read side XORs byte offset by (row&7)<<4. Uniform 8 lanes/slot -> conflict-free b128.
// XCD locality: n0 from blockIdx.x (id%8) -> each XCD pins its 4MB B-panel set in L2.
struct ProjArgs {
  const u16* xh;
  const u16* wT0; const u16* wT1; const u16* wT2; const u16* wT3;
  u16* q; u16* k; u16* v; u16* vg;
  const float* bvg;
};
__global__ __launch_bounds__(512) void k_proj2(ProjArgs p){
  __shared__ __align__(16) u16 ldsA[2][16384];   // [buf][256 rows x 64 k], 32KB each
  __shared__ __align__(16) u16 ldsB[2][16384];
  const int z = blockIdx.z;
  const u16* wT = (z==0) ? p.wT0 : (z==1) ? p.wT1 : (z==2) ? p.wT2 : p.wT3;
  const int m0 = blockIdx.y << 8, n0 = blockIdx.x << 8;
  const int tid = threadIdx.x, w = tid >> 6, l = tid & 63;
  const int wm = w >> 2, wn = w & 3, qq = l >> 4, m = l & 15;
  const int cxor = (m & 7) * 8;                      // read-side swizzle: slot ^= row&7 (elem units)
  const int lrow = l >> 3;
  const int lcol = (((l & 7) ^ (l >> 3)) * 8);       // inverse-swizzled source col (elem units)
  const u16* aSrc = p.xh + (size_t)(m0 + lrow) * 2048 + lcol;
  const u16* bSrc = wT   + (size_t)(n0 + lrow) * 2048 + lcol;
  const int wp2 = w * 2;

  f32x4 acc[8][4];
  { f32x4 zr = {0.f,0.f,0.f,0.f};
    #pragma unroll
    for (int i=0;i<8;i++)
      #pragma unroll
      for (int j=0;j<4;j++) acc[i][j] = zr; }

#define STGA(buf,h,kt) do{ \
    async16(aSrc + (size_t)((h)*128 + wp2*8)*2048 + (kt)*64,     &ldsA[buf][(h)*8192 + wp2*512]); \
    async16(aSrc + (size_t)((h)*128 + (wp2+1)*8)*2048 + (kt)*64, &ldsA[buf][(h)*8192 + (wp2+1)*512]); }while(0)
#define STGB(buf,h,kt) do{ \
    async16(bSrc + (size_t)((h)*128 + wp2*8)*2048 + (kt)*64,     &ldsB[buf][(h)*8192 + wp2*512]); \
    async16(bSrc + (size_t)((h)*128 + (wp2+1)*8)*2048 + (kt)*64, &ldsB[buf][(h)*8192 + (wp2+1)*512]); }while(0)
#define RDA(buf,i,s) (*(const f16x8*)(&ldsA[buf][(wm*128 + (i)*16 + m)*64 + (((s)*32 + qq*8) ^ cxor)]))
#define RDB(buf,j,s) (*(const f16x8*)(&ldsB[buf][(wn*64 + (j)*16 + m)*64 + (((s)*32 + qq*8) ^ cxor)]))

  f16x8 bf[4][2];
#define RDBALL(buf) do{ \
    _Pragma("unroll") \
    for (int j=0;j<4;j++){ bf[j][0] = RDB(buf,j,0); bf[j][1] = RDB(buf,j,1); } }while(0)
#define VMW asm volatile("s_waitcnt vmcnt(4)" ::: "memory")
#define PHASE(buf,i0,BSTMT,SSTMT,VMSTMT) do{ \
    f16x8 a00 = RDA(buf,(i0),0),   a01 = RDA(buf,(i0),1); \
    f16x8 a10 = RDA(buf,(i0)+1,0), a11 = RDA(buf,(i0)+1,1); \
    BSTMT; \
    SSTMT; \
    __builtin_amdgcn_s_barrier(); \
    asm volatile("s_waitcnt lgkmcnt(0)" ::: "memory"); \
    __builtin_amdgcn_s_setprio(1); \
    _Pragma("unroll") \
    for (int j=0;j<4;j++){ \
      acc[(i0)][j]   = __builtin_amdgcn_mfma_f32_16x16x32_f16(a00, bf[j][0], acc[(i0)][j],   0,0,0); \
      acc[(i0)][j]   = __builtin_amdgcn_mfma_f32_16x16x32_f16(a01, bf[j][1], acc[(i0)][j],   0,0,0); \
      acc[(i0)+1][j] = __builtin_amdgcn_mfma_f32_16x16x32_f16(a10, bf[j][0], acc[(i0)+1][j], 0,0,0); \
      acc[(i0)+1][j] = __builtin_amdgcn_mfma_f32_16x16x32_f16(a11, bf[j][1], acc[(i0)+1][j], 0,0,0); \
    } \
    __builtin_amdgcn_s_setprio(0); \
    VMSTMT; \
    __builtin_amdgcn_s_barrier(); }while(0)

  // prologue: tile0 A+B -> buf0; tile1 B -> buf1. 12 loads, wait all but newest 4.
  STGA(0,0,0); STGA(0,1,0); STGB(0,0,0); STGB(0,1,0); STGB(1,0,1); STGB(1,1,1);
  VMW;
  __builtin_amdgcn_s_barrier();

  for (int u = 0; u < 16; u++){
    const int t1 = 2*u+1, t2 = (2*u+2)&31, t3 = (2*u+3)&31;   // wrapped tail prefetch (harmless)
    PHASE(0,0, RDBALL(0), STGA(1,0,t1), ((void)0));
    PHASE(0,2, ((void)0), STGA(1,1,t1), ((void)0));
    PHASE(0,4, ((void)0), STGB(0,0,t2), ((void)0));
    PHASE(0,6, ((void)0), STGB(0,1,t2), VMW);
    PHASE(1,0, RDBALL(1), STGA(0,0,t2), ((void)0));
    PHASE(1,2, ((void)0), STGA(0,1,t2), ((void)0));
    PHASE(1,4, ((void)0), STGB(1,0,t3), ((void)0));
    PHASE(1,6, ((void)0), STGB(1,1,t3), VMW);
  }

  u16* dst3 = (z==0) ? p.q : (z==1) ? p.k : p.v;
  #pragma unroll
  for (int i=0;i<8;i++)
  #pragma unroll
  for (int j=0;j<4;j++)
  #pragma unroll
  for (int r=0;r<4;r++){
    int gr = m0 + wm*128 + i*16 + qq*4 + r;
    int gc = n0 + wn*64 + j*16 + m;
    float v = acc[i][j][r];
    if (z == 3){
      p.vg[(size_t)gr*2048 + gc] = f2h(sigm(v + p.bvg[gc]));
    } else {
      int b = gr >> 10, ii = gr & 1023, h = gc >> 7, d = gc & 127;
      dst3[(((size_t)(b*16 + h))*1024 + ii)*128 + d] = f2h(v);
    }
  }
#undef STGA
#undef STGB
#undef RDA
#undef RDB
#undef RDBALL
#undef VMW
#undef PHASE
}

// ---------------- fused mid: hgate (blocks 0..127) + v-transpose (128..4223) + normrope (4224..20607) ----------------
struct MidArgs {
  const u16* xh; const u16* whgT; const float* bhg; float* hg;     // hgate
  const u16* vb; u16* vTT;                                          // transpose
  u16* qb; u16* kb; const float* freqs; const float* cope; float* L; // normrope
};
__global__ __launch_bounds__(256) void k_mid(MidArgs p){
  __shared__ float red[4][256];
  __shared__ u16 t[32][33];
  __shared__ float ce[2048];
  int bz = blockIdx.x;
  int tid = threadIdx.x;
  if (bz < 128){
    // ---- hgate ----
    int w = tid>>6, l = tid&63, q = l>>4, m = l&15;
    int t0 = bz*16;
    f32x4 acc = {0.f,0.f,0.f,0.f};
    const u16* xr = p.xh   + (size_t)(t0 + m)*2048 + w*512;
    const u16* br = p.whgT + (size_t)m*2048 + w*512;
    #pragma unroll 4
    for (int k = 0; k < 512; k += 32){
      f16x8 a = *(const f16x8*)(xr + k + q*8);
      f16x8 b = *(const f16x8*)(br + k + q*8);
      acc = __builtin_amdgcn_mfma_f32_16x16x32_f16(a, b, acc, 0, 0, 0);
    }
    #pragma unroll
    for (int r = 0; r < 4; r++) red[w][(q*4+r)*16 + m] = acc[r];
    __syncthreads();
    float v = red[0][tid] + red[1][tid] + red[2][tid] + red[3][tid];
    int tl = tid >> 4, h = tid & 15;
    p.hg[(size_t)(t0 + tl)*16 + h] = sigm(v + p.bhg[h]);
    return;
  }
  if (bz < 4224){
    // ---- v transpose [1024][128] -> [128][1024], 32 batches ----
    int f = bz - 128;
    int zb = f >> 7, rem = f & 127;
    int by = rem >> 2, bx = rem & 3;
    const u16* src = p.vb + (size_t)zb*131072;
    u16* dst = p.vTT + (size_t)zb*131072;
    int c0 = bx*32, r0 = by*32;
    int tx = tid & 31, ty = tid >> 5;
    #pragma unroll
    for (int i = ty; i < 32; i += 8){
      int r = r0 + i, c = c0 + tx;
      t[i][tx] = src[(size_t)r*128 + c];
    }
    __syncthreads();
    #pragma unroll
    for (int i = ty; i < 32; i += 8){
      int rr = c0 + i, cc = r0 + tx;
      dst[(size_t)rr*1024 + cc] = t[tx][i];
    }
    return;
  }
  // ---- normrope ----
  {
    int bx = bz - 4224;
    for (int i2 = tid; i2 < 2048; i2 += 256) ce[i2] = p.cope[i2];
    __syncthreads();
    int w = tid >> 6, l = tid & 63;
    int r = bx*4 + w;                  // 0..65535
    int isq = (r < 32768) ? 1 : 0;
    int rr = isq ? r : r - 32768;
    int i = rr & 1023;
    u16* base = (isq ? p.qb : p.kb) + (size_t)rr*128;
    float v0 = h2f(base[2*l]), v1 = h2f(base[2*l+1]);
    float ss = v0*v0 + v1*v1;
    #pragma unroll
    for (int off = 1; off < 64; off <<= 1) ss += __shfl_xor(ss, off);
    float rn = 1.f / fmaxf(sqrtf(ss), 1e-12f);
    v0 *= rn; v1 *= rn;
    float f = p.freqs[i*128 + 2*l];
    float sn, cs; sincosf(f, &sn, &cs);
    float o0 = v0*cs - v1*sn, o1 = v1*cs + v0*sn;
    base[2*l] = f2h(o0); base[2*l+1] = f2h(o1);
    if (isq){
      #pragma unroll
      for (int pp = 0; pp < 16; pp++){
        float part = o0*ce[pp*128 + 2*l] + o1*ce[pp*128 + 2*l + 1];
        #pragma unroll
        for (int off = 1; off < 64; off <<= 1) part += __shfl_xor(part, off);
        if (l == pp) p.L[(size_t)rr*16 + pp] = part;
      }
    }
  }
}

// ---------------- sim = 10*q k^T: A-resident 64-row tile, loop j-tiles ----------------
__global__ __launch_bounds__(256) void k_qk(const u16* __restrict__ qb, const u16* __restrict__ kb,
    u16* __restrict__ S){
  __shared__ __align__(16) u16 As[8192];    // 4 chunks x 64 rows x 32
  __shared__ __align__(16) u16 Bs[16384];   // 4 chunks x 128 rows x 32
  int bh = blockIdx.y;
  int bx = 15 - (int)blockIdx.x;            // heavy blocks first
  int i0 = bx*64, it = bx >> 1;
  int njt = (bx + 2) >> 1;
  int tid = threadIdx.x, w = tid>>6, l = tid&63, q = l>>4, m = l&15, wm = w&1, wn = w>>1;
  const u16* qbase = qb + (size_t)bh*131072;
  const u16* kbase = kb + (size_t)bh*131072;
  // stage A once (resident)
  #pragma unroll
  for (int sub = 0; sub < 4; sub++){
    int row = w*16 + (l>>2);
    async16(qbase + (size_t)(i0 + row)*128 + sub*32 + (l&3)*8, As + sub*2048 + (w*16)*32);
  }
  u16* dstbase = S + ((size_t)bh*36 + (it*(it+1))/2)*16384 + (size_t)((bx&1)*64)*128;
  for (int jt = 0; jt < njt; jt++){
    __syncthreads();
    #pragma unroll
    for (int sub = 0; sub < 4; sub++)
      #pragma unroll
      for (int p = 0; p < 2; p++){
        int row = w*32 + p*16 + (l>>2);
        async16(kbase + (size_t)(jt*128 + row)*128 + sub*32 + (l&3)*8,
                Bs + sub*4096 + (w*32 + p*16)*32);
      }
    __syncthreads();
    f32x4 acc[2][4];
    { f32x4 z = {0.f,0.f,0.f,0.f};
      #pragma unroll
      for (int a2=0;a2<2;a2++)
        #pragma unroll
        for (int b2=0;b2<4;b2++) acc[a2][b2] = z; }
    #pragma unroll
    for (int kc = 0; kc < 4; kc++){
      f16x8 af[2], bf[4];
      #pragma unroll
      for (int t = 0; t < 2; t++) af[t] = *(const f16x8*)(As + kc*2048 + (wm*32 + t*16 + m)*32 + q*8);
      #pragma unroll
      for (int t = 0; t < 4; t++) bf[t] = *(const f16x8*)(Bs + kc*4096 + (wn*64 + t*16 + m)*32 + q*8);
      #pragma unroll
      for (int a2 = 0; a2 < 2; a2++)
        #pragma unroll
        for (int b2 = 0; b2 < 4; b2++)
          acc[a2][b2] = __builtin_amdgcn_mfma_f32_16x16x32_f16(af[a2], bf[b2], acc[a2][b2], 0, 0, 0);
    }
    u16* dst = dstbase + (size_t)jt*16384;
    #pragma unroll
    for (int ti=0; ti<2; ti++)
    #pragma unroll
    for (int tj=0; tj<4; tj++)
    #pragma unroll
    for (int r=0; r<4; r++){
      int iloc = wm*32 + ti*16 + q*4 + r;
      int jloc = wn*64 + tj*16 + m;
      float v = acc[ti][tj][r] * 10.f;
      if (jt*128 + jloc > i0 + iloc) v = MASKV;
      dst[(size_t)iloc*128 + jloc] = f2h(v);
    }
  }
}

// ---------------- th_pre mix + CoPE + online softmax stats (in-place S) ----------------
struct CopeArgs { const u16* S; const float* L; const float* thpre; u16* Sout; float* ml; };
__global__ __launch_bounds__(1024) void k_cope(CopeArgs pa){
  __shared__ u16 raw[16*276];       // [g][ii*68 + j], padded strides: conflict-free b64
  __shared__ float thsh[256];       // th_pre[h][g]
  __shared__ float Lsh[1024];       // [h][ii][p]
  int b = blockIdx.y;
  int i0 = (int)(gridDim.x - 1 - blockIdx.x) * 4;   // heavy blocks first
  int tid = threadIdx.x, w = tid>>6, l = tid&63;
  int h = w;                                         // 16 waves = 16 heads
  if (tid < 256) thsh[tid] = pa.thpre[tid];
  Lsh[tid] = pa.L[ ((size_t)((b*16 + (tid>>6))*1024) + i0 + ((tid>>4)&3))*16 + (tid&15) ];
  __syncthreads();
  float th_r[16];
  #pragma unroll
  for (int g = 0; g < 16; g++) th_r[g] = thsh[h*16 + g];
  int ii = l >> 4, j0 = (l & 15)*4;
  int i = i0 + ii, it1 = i >> 7, iloc = i & 127;
  const float* Lrow = Lsh + h*64 + ii*16;
  float carry = 0.f, mrun = -1e30f, lrun = 0.f;
  int tmax = (i0 + 3) >> 6;
  for (int t = tmax; t >= 0; t--){
    int jt1 = (t*64) >> 7, jo = (t*64) & 127;
    __syncthreads();
    {
      int e = tid*4;                 // [0,4096)
      int g = e >> 8, r = e & 255;
      int si = r >> 6, j = r & 63;
      int irow = i0 + si; int it2 = irow >> 7, il2 = irow & 127;
      const u16* src = pa.S + ((size_t)((b*16+g)*36 + (it2*(it2+1))/2 + jt1))*16384
                           + (size_t)il2*128 + jo + j;
      *(u16x4*)(raw + g*276 + si*68 + j) = *(const u16x4*)src;
    }
    __syncthreads();
    float s0=0.f, s1=0.f, s2=0.f, s3=0.f;
    #pragma unroll
    for (int g = 0; g < 16; g++){
      u16x4 v = *(const u16x4*)(raw + g*276 + ii*68 + j0);
      float tg = th_r[g];
      s0 += tg*h2f(v[0]); s1 += tg*h2f(v[1]); s2 += tg*h2f(v[2]); s3 += tg*h2f(v[3]);
    }
    // gates + segmented suffix scan (in-lane 4 + cross-lane 16)
    float g0 = sigm(s0), g1 = sigm(s1), g2 = sigm(s2), g3 = sigm(s3);
    float c3 = g3, c2 = g2 + c3, c1 = g1 + c2, c0 = g0 + c1;
    float T = c0, Tacc = T;
    #pragma unroll
    for (int off = 1; off < 16; off <<= 1){
      float tv = __shfl(Tacc, (l + off) & 63);
      if (((l & 15) + off) < 16) Tacc += tv;
    }
    float Rh = Tacc - T;                         // sum over higher lanes in group
    float rowtot = __shfl(Tacc, l & 48);         // group-first lane = full tile sum
    float sf[4];
    float cc[4] = {c0, c1, c2, c3};
    float ssv[4] = {s0, s1, s2, s3};
    #pragma unroll
    for (int c = 0; c < 4; c++){
      float pos = fminf(cc[c] + Rh + carry, 15.f);
      float pf = floorf(pos);
      float wi = pos - pf;
      int ic = (int)ceilf(pos), ifl = (int)pf;
      float v = ssv[c] + Lrow[ic]*wi + Lrow[ifl]*(1.f - wi);
      sf[c] = v;
    }
    carry += rowtot;
    u16x4 ov;
    #pragma unroll
    for (int c = 0; c < 4; c++){ ov[c] = f2h(sf[c]); sf[c] = h2f(ov[c]); }
    *(u16x4*)(pa.Sout + ((size_t)((b*16+h)*36 + (it1*(it1+1))/2 + jt1))*16384
              + (size_t)iloc*128 + jo + j0) = ov;
    float M = fmaxf(fmaxf(sf[0], sf[1]), fmaxf(sf[2], sf[3]));
    #pragma unroll
    for (int off = 1; off < 16; off <<= 1) M = fmaxf(M, __shfl_xor(M, off));
    float mnew = fmaxf(mrun, M);
    float es = __expf(fminf(sf[0]-mnew,0.f)) + __expf(fminf(sf[1]-mnew,0.f))
             + __expf(fminf(sf[2]-mnew,0.f)) + __expf(fminf(sf[3]-mnew,0.f));
    #pragma unroll
    for (int off = 1; off < 16; off <<= 1) es += __shfl_xor(es, off);
    lrun = lrun*__expf(fminf(mrun - mnew, 0.f)) + es;
    mrun = mnew;
  }
  if ((l & 15) == 0){
    size_t bix = (size_t)(b*16 + h)*1024 + i0 + ii;
    pa.ml[bix] = mrun;
    pa.ml[32768 + bix] = 1.f/fmaxf(lrun, 1e-30f);
  }
}

// ---------------- softmax normalize + th_post mix (packed fp16, in-place S -> attn2) ----------------
struct PostArgs { const u16* S; const float* ml; const float* thpost; u16* Sout; };
__global__ __launch_bounds__(256) void k_postmix(PostArgs pa){
  __shared__ u16 at[16*1040];        // [g][e], stride 1040
  __shared__ _Float16 thsh[256];
  __shared__ float mh[128], rlh[128];
  int tile = blockIdx.x >> 4, sub = blockIdx.x & 15, b = blockIdx.y;
  int it = 0;
  #pragma unroll
  for (int t2=1; t2<8; t2++) if (tile >= (t2*(t2+1))/2) it = t2;
  int tid = threadIdx.x;
  thsh[tid] = (_Float16)pa.thpost[tid];
  if (tid < 128){
    int g = tid >> 3, ii = tid & 7;
    size_t ix = (size_t)(b*16+g)*1024 + it*128 + sub*8 + ii;
    mh[tid] = pa.ml[ix]; rlh[tid] = pa.ml[32768 + ix];
  }
  __syncthreads();
  {
    int g = tid >> 4, l16 = tid & 15;
    const u16* src = pa.S + ((size_t)((b*16+g)*36 + tile))*16384 + sub*1024;
    #pragma unroll
    for (int c = 0; c < 16; c++){
      int e = c*64 + l16*4;
      int ii = e >> 7;
      float mm = mh[g*8+ii], rr = rlh[g*8+ii];
      u16x4 sv = *(const u16x4*)(src + e);
      u16x4 o;
      #pragma unroll
      for (int z2=0; z2<4; z2++) o[z2] = f2h(__expf(fminf(h2f(sv[z2]) - mm, 0.f)) * rr);
      *(u16x4*)(at + g*1040 + e) = o;
    }
  }
  __syncthreads();
  int h = tid >> 4, c16 = tid & 15;
  _Float16 th_h[16];
  #pragma unroll
  for (int g = 0; g < 16; g++) th_h[g] = thsh[h*16 + g];
  u16* dst = pa.Sout + ((size_t)((b*16+h)*36 + tile))*16384 + sub*1024;
  #pragma unroll
  for (int k = 0; k < 16; k++){
    int e = c16*4 + k*64;
    f16x4 a = {0,0,0,0};
    #pragma unroll
    for (int g = 0; g < 16; g++){
      f16x4 v = *(const f16x4*)(at + g*1040 + e);
      a += v * th_h[g];
    }
    *(f16x4*)(dst + e) = a;
  }
}

// ---------------- out = attn2 @ v, fused head/value gates, BK=128 chunks ----------------
struct PvArgs { const u16* S; const u16* vT; const float* hg; const u16* vg; u16* gated; };
__global__ __launch_bounds__(256) void k_pv(PvArgs pa){
  __shared__ __align__(16) u16 As[8192];    // 4 sub x 64 rows x 32
  __shared__ __align__(16) u16 Bs[16384];   // 4 sub x 128 rows x 32
  int bh = blockIdx.y, b = bh >> 4, h = bh & 15;
  int bx = 15 - (int)blockIdx.x;            // heavy blocks first
  int i0 = bx*64, it = bx >> 1;
  int nc = (bx + 2) >> 1;
  int tid = threadIdx.x, w = tid>>6, l = tid&63, q = l>>4, m = l&15, wm = w&1, wn = w>>1;
  const u16* abase = pa.S + ((size_t)bh*36 + (it*(it+1))/2)*16384 + (size_t)((bx&1)*64)*128;
  const u16* vt    = pa.vT + (size_t)bh*131072;
  f32x4 acc[2][4];
  { f32x4 z = {0.f,0.f,0.f,0.f};
    #pragma unroll
    for (int a2=0;a2<2;a2++)
      #pragma unroll
      for (int b2=0;b2<4;b2++) acc[a2][b2] = z; }
  for (int jc = 0; jc < nc; jc++){
    __syncthreads();
    #pragma unroll
    for (int sub = 0; sub < 4; sub++){
      int row = w*16 + (l>>2);
      async16(abase + (size_t)jc*16384 + (size_t)row*128 + sub*32 + (l&3)*8,
              As + sub*2048 + (w*16)*32);
      #pragma unroll
      for (int p = 0; p < 2; p++){
        int brow = w*32 + p*16 + (l>>2);
        async16(vt + (size_t)brow*1024 + jc*128 + sub*32 + (l&3)*8,
                Bs + sub*4096 + (w*32 + p*16)*32);
      }
    }
    __syncthreads();
    #pragma unroll
    for (int kc = 0; kc < 4; kc++){
      f16x8 af[2], bf[4];
      #pragma unroll
      for (int t = 0; t < 2; t++) af[t] = *(const f16x8*)(As + kc*2048 + (wm*32 + t*16 + m)*32 + q*8);
      #pragma unroll
      for (int t = 0; t < 4; t++) bf[t] = *(const f16x8*)(Bs + kc*4096 + (wn*64 + t*16 + m)*32 + q*8);
      #pragma unroll
      for (int a2 = 0; a2 < 2; a2++)
        #pragma unroll
        for (int b2 = 0; b2 < 4; b2++)
          acc[a2][b2] = __builtin_amdgcn_mfma_f32_16x16x32_f16(af[a2], bf[b2], acc[a2][b2], 0, 0, 0);
    }
  }
  #pragma unroll
  for (int ti=0; ti<2; ti++)
  #pragma unroll
  for (int tj=0; tj<4; tj++)
  #pragma unroll
  for (int r=0; r<4; r++){
    int i = i0 + wm*32 + ti*16 + q*4 + r;
    int d = wn*64 + tj*16 + m;
    int tok = b*1024 + i;
    float v = acc[ti][tj][r] * pa.hg[(size_t)tok*16 + h] * h2f(pa.vg[(size_t)tok*2048 + h*128 + d]);
    if (v != v) v = 333.f;           // NaN tag: PV-level
    pa.gated[(size_t)tok*2048 + h*128 + d] = f2h(v);
  }
}

// ---------------- final projection -> f32 d_out (M=64 tiles, 512 blocks) ----------------
__global__ __launch_bounds__(256) void k_out(const u16* __restrict__ gated, const u16* __restrict__ woT,
    float* __restrict__ out){
  __shared__ __align__(16) u16 As[2048];
  __shared__ __align__(16) u16 Bs[4096];
  int bx = blockIdx.x;                // col tile (16)
  int by = blockIdx.y;                // row tile (32)
  int trow0 = by*64, c0 = bx*128;
  int tid = threadIdx.x, w = tid>>6, l = tid&63, q = l>>4, m = l&15, wm = w&1, wn = w>>1;
  f32x4 acc[2][4];
  { f32x4 z = {0.f,0.f,0.f,0.f};
    #pragma unroll
    for (int a2=0;a2<2;a2++)
      #pragma unroll
      for (int b2=0;b2<4;b2++) acc[a2][b2] = z; }
  for (int k0 = 0; k0 < 2048; k0 += 32){
    __syncthreads();
    {
      int row = w*16 + (l>>2);
      async16(gated + (size_t)(trow0 + row)*2048 + k0 + (l&3)*8, As + (w*16)*32);
    }
    #pragma unroll
    for (int p = 0; p < 2; p++){
      int row = w*32 + p*16 + (l>>2);
      async16(woT + (size_t)(c0 + row)*2048 + k0 + (l&3)*8, Bs + (w*32 + p*16)*32);
    }
    __syncthreads();
    f16x8 af[2], bf[4];
    #pragma unroll
    for (int t = 0; t < 2; t++) af[t] = *(const f16x8*)(As + (wm*32 + t*16 + m)*32 + q*8);
    #pragma unroll
    for (int t = 0; t < 4; t++) bf[t] = *(const f16x8*)(Bs + (wn*64 + t*16 + m)*32 + q*8);
    #pragma unroll
    for (int a2 = 0; a2 < 2; a2++)
      #pragma unroll
      for (int b2 = 0; b2 < 4; b2++)
        acc[a2][b2] = __builtin_amdgcn_mfma_f32_16x16x32_f16(af[a2], bf[b2], acc[a2][b2], 0, 0, 0);
  }
  #pragma unroll
  for (int ti=0; ti<2; ti++)
  #pragma unroll
  for (int tj=0; tj<4; tj++)
  #pragma unroll
  for (int r=0; r<4; r++){
    int trow = trow0 + wm*32 + ti*16 + q*4 + r;
    int col  = c0 + wn*64 + tj*16 + m;
    float o = acc[ti][tj][r];
    if (o != o) o = 911.f;           // NaN tag: output-GEMM level
    out[(size_t)trow*2048 + col] = o;
  }
}

extern "C" void kernel_launch(void* const* d_in, const int* in_sizes, int n_in,
                              void* d_out, int out_size, void* d_ws, size_t ws_size,
                              hipStream_t stream){
  const float* x      = (const float*)d_in[0];
  const float* freqs  = (const float*)d_in[1];
  const float* w_q    = (const float*)d_in[2];
  const float* w_k    = (const float*)d_in[3];
  const float* w_v    = (const float*)d_in[4];
  const float* cope   = (const float*)d_in[5];
  const float* thpre  = (const float*)d_in[6];
  const float* thpost = (const float*)d_in[7];
  const float* w_vg   = (const float*)d_in[8];
  const float* b_vg   = (const float*)d_in[9];
  const float* w_hg   = (const float*)d_in[10];
  const float* b_hg   = (const float*)d_in[11];
  const float* w_out  = (const float*)d_in[12];

  char* ws = (char*)d_ws;
  size_t off = 0;
  auto alloc = [&](size_t bytes)->char*{ char* r = ws + off; off += (bytes + 255) & ~(size_t)255; return r; };
  u16*   xh    = (u16*)  alloc(8388608);
  u16*   wqT   = (u16*)  alloc(8388608);
  u16*   wkT   = (u16*)  alloc(8388608);
  u16*   wvT   = (u16*)  alloc(8388608);
  u16*   wvgT  = (u16*)  alloc(8388608);
  u16*   woT   = (u16*)  alloc(8388608);
  u16*   whgT  = (u16*)  alloc(65536);
  u16*   qb    = (u16*)  alloc(8388608);
  u16*   kb    = (u16*)  alloc(8388608);
  u16*   vb    = (u16*)  alloc(8388608);
  u16*   vTT   = (u16*)  alloc(8388608);
  u16*   vg    = (u16*)  alloc(8388608);
  u16*   gated = (u16*)  alloc(8388608);
  float* L     = (float*)alloc(2097152);
  float* hg    = (float*)alloc(131072);
  float* ml    = (float*)alloc(262144);
  u16*   S     = (u16*)  alloc(37748736);

  dim3 b256(256);
  PrepArgs pp;
  pp.src[0]=x;    pp.dst[0]=xh;   pp.C[0]=2048;
  pp.src[1]=w_q;  pp.dst[1]=wqT;  pp.C[1]=2048;
  pp.src[2]=w_k;  pp.dst[2]=wkT;  pp.C[2]=2048;
  pp.src[3]=w_v;  pp.dst[3]=wvT;  pp.C[3]=2048;
  pp.src[4]=w_vg; pp.dst[4]=wvgT; pp.C[4]=2048;
  pp.src[5]=w_out;pp.dst[5]=woT;  pp.C[5]=2048;
  pp.src[6]=w_hg; pp.dst[6]=whgT; pp.C[6]=16;
  k_prep<<<dim3(32,32,7), b256, 0, stream>>>(pp);

  ProjArgs pa{ xh, wqT, wkT, wvT, wvgT, qb, kb, vb, vg, b_vg };
  k_proj2<<<dim3(8,8,4), dim3(512), 0, stream>>>(pa);
  MidArgs ma{ xh, whgT, b_hg, hg, vb, vTT, qb, kb, freqs, cope, L };
  k_mid<<<dim3(20608), b256, 0, stream>>>(ma);
  k_qk<<<dim3(16,32), b256, 0, stream>>>(qb, kb, S);
  CopeArgs ca{ S, L, thpre, S, ml };
  k_cope<<<dim3(256,2), dim3(1024), 0, stream>>>(ca);
  PostArgs po{ S, ml, thpost, S };
  k_postmix<<<dim3(576,2), b256, 0, stream>>>(po);
  PvArgs pv{ S, vTT, hg, vg, gated };
  k_pv<<<dim3(16,32), b256, 0, stream>>>(pv);
  k_out<<<dim3(16,32), b256, 0, stream>>>(gated, woT, (float*)d_out);
}